// Round 7
// baseline (2470.243 us; speedup 1.0000x reference)
//
#include <hip/hip_runtime.h>
#include <hip/hip_bf16.h>

// GenericLSTM: B=64 T=2048 I=128 H=256, fp32 in/out.
// Plan: (1) pack W_h -> int8 MFMA A-fragments (transposed form) + per-col
// scales, (2) pack W_x -> bf16 in MFMA fragment order, (3) one MFMA GEMM
// computes g_x = inputs@W_x for all t (f16), (4) persistent recurrent kernel:
// 1 WG/sample, 1024 threads (16 waves, 4/SIMD). Recurrent matvec h@W_h runs
// on the MATRIX pipe via mfma_i32_16x16x64_i8: A = W^T frags (constant, in
// registers), B = h int8 broadcast from LDS (every lane supplies the same h
// bytes for its k-block -> all 16 B-columns compute the same correct result).
// Rounds 3-5 showed the VALU dot4 path costs ~5-6cyc/dot -> ~1500cyc/step
// floor; MFMA pipe does the same work in ~1280cyc while VALU runs the tail.

#define B_ 64
#define T_ 2048
#define I_ 128
#define H_ 256
#define NC 1024  // 4 gates * H columns

typedef __attribute__((ext_vector_type(8))) short bf16x8;
typedef __attribute__((ext_vector_type(4))) float f32x4;
typedef __attribute__((ext_vector_type(4))) int i32x4;

static __device__ __forceinline__ unsigned short f2bf(float f) {
    unsigned u = __builtin_bit_cast(unsigned, f);
    u = (u + 0x7FFFu + ((u >> 16) & 1u)) >> 16;
    return (unsigned short)u;
}

static __device__ __forceinline__ float fastrcp(float x) {
    return __builtin_amdgcn_rcpf(x);
}

// ---------------- P1: W_h [4,256,256] f32 -> int8 packed directly as
// mfma_i32_16x16x64_i8 A-fragments (transposed: A[m=gatecol][k]) + per-col
// scale (scale already includes the 1/127 h dequant factor).
// Frag addressing: frag id = ((j>>4)*4 + g)*4 + kt ; within frag, lane fl
// holds row (fl&15)=j&15, k-block (fl>>4), bytes = k offset 0..15.
// pack_wh thread (col, lane) covers k = 4*lane..4*lane+3:
//   kt = lane>>4, kblock = (lane&15)>>2, dword-in-frag = lane&3.
__global__ void pack_wh(const float* __restrict__ Wh, unsigned* __restrict__ afr,
                        float* __restrict__ sws) {
    int col = blockIdx.x;              // 0..1023 = g*256 + j
    int g = col >> 8, j = col & 255;
    int lane = threadIdx.x;            // 0..63, covers k = 4*lane..4*lane+3
    float v[4];
    float m = 0.f;
#pragma unroll
    for (int u = 0; u < 4; ++u) {
        int k = lane * 4 + u;
        v[u] = Wh[(g * H_ + k) * H_ + j];
        m = fmaxf(m, fabsf(v[u]));
    }
#pragma unroll
    for (int off = 32; off; off >>= 1) m = fmaxf(m, __shfl_xor(m, off));
    float mm = (m > 0.f) ? m : 1.f;
    float inv = 127.f / mm;
    unsigned pack = 0;
#pragma unroll
    for (int u = 0; u < 4; ++u) {
        int q = (int)rintf(v[u] * inv);
        q = max(-127, min(127, q));
        pack |= ((unsigned)(q & 255)) << (8 * u);
    }
    int fragid = ((j >> 4) * 4 + g) * 4 + (lane >> 4);
    int fl = (((lane & 15) >> 2) * 16) + (j & 15);
    int didx = (fragid * 64 + fl) * 4 + (lane & 3);
    afr[didx] = pack;
    if (lane == 0) sws[col] = mm / (127.f * 127.f);  // S_col/127
}

// ---------------- P2: W_x [4,128,256] f32 -> bf16 in MFMA-fragment order:
// Bfrag[((ki*4+q)*1024 + col)*8 + j] = W_x[g][k][h], k = (ki)*32 + q*8 + j.
__global__ void pack_wx(const float* __restrict__ Wx,
                        unsigned short* __restrict__ bxp) {
    int f = blockIdx.x * blockDim.x + threadIdx.x;  // 0..131071
    int j = f & 7;
    int col = (f >> 3) & 1023;
    int c16 = f >> 13;  // 0..15
    int k = (c16 >> 2) * 32 + (c16 & 3) * 8 + j;
    int g = col >> 8, h = col & 255;
    bxp[f] = f2bf(Wx[(g * I_ + k) * H_ + h]);
}

// ---------------- GEMM: g_x[row][col] = sum_k inputs[row][k] * W_x[k][col]
// rows = b*T+t (131072), cols = 1024, K = 128 (single shot, no k-loop).
// Output stored as f16.
__global__ __launch_bounds__(256) void gemm_gx(
    const float* __restrict__ A, const unsigned short* __restrict__ Bp,
    unsigned short* __restrict__ Cg) {
    __shared__ uint4 sm[4096];  // 64 KB: As = [0..2047], Bs = [2048..4095]
    int tid = threadIdx.x;
    int mt = blockIdx.x, nt = blockIdx.y;

    // Stage A tile (128 rows x 128 k), f32 -> bf16, fragment-order layout:
    // As[(c16*128+m)] is a 16B vector holding k-j 0..7 for that (c16,m).
    const float* Ab = A + (size_t)mt * 128 * I_;
    unsigned* dstA = (unsigned*)sm;
#pragma unroll
    for (int it = 0; it < 16; ++it) {
        int flat = it * 1024 + tid * 4;
        float4 a4 = *(const float4*)(Ab + flat);
        int m = flat >> 7, k0 = flat & 127;
        int c16 = k0 >> 3, j0 = k0 & 7;  // j0 in {0,4}
        unsigned lo = (unsigned)f2bf(a4.x) | ((unsigned)f2bf(a4.y) << 16);
        unsigned hi = (unsigned)f2bf(a4.z) | ((unsigned)f2bf(a4.w) << 16);
        int didx = ((c16 * 128 + m) * 16 + j0 * 2) >> 2;
        dstA[didx] = lo;
        dstA[didx + 1] = hi;
    }
    // Stage B tile (prepacked fragment order): contiguous 16B per (c16,col).
    const uint4* Bq = (const uint4*)Bp;
#pragma unroll
    for (int it = 0; it < 8; ++it) {
        int chunk = it * 2 + (tid >> 7);
        int inner = tid & 127;
        sm[2048 + chunk * 128 + inner] = Bq[chunk * 1024 + nt * 128 + inner];
    }
    __syncthreads();

    int wid = tid >> 6, lane = tid & 63;
    int r = lane & 15, q = lane >> 4;
    int mw = (wid & 1) * 64, nw = (wid >> 1) * 64;
    f32x4 acc[4][4] = {};
#pragma unroll
    for (int ki = 0; ki < 4; ++ki) {
        bf16x8 af[4], bfr[4];
#pragma unroll
        for (int x = 0; x < 4; ++x) {
            af[x] = __builtin_bit_cast(bf16x8,
                                       sm[(ki * 4 + q) * 128 + mw + x * 16 + r]);
            bfr[x] = __builtin_bit_cast(
                bf16x8, sm[2048 + (ki * 4 + q) * 128 + nw + x * 16 + r]);
        }
#pragma unroll
        for (int x = 0; x < 4; ++x)
#pragma unroll
            for (int y = 0; y < 4; ++y)
                acc[x][y] = __builtin_amdgcn_mfma_f32_16x16x32_bf16(
                    af[x], bfr[y], acc[x][y], 0, 0, 0);
    }
    __syncthreads();

    // C frags (col=lane&15, row=q*4+reg) -> LDS f16 tile, then coalesced store.
    _Float16* ct = (_Float16*)sm;
#pragma unroll
    for (int x = 0; x < 4; ++x)
#pragma unroll
        for (int y = 0; y < 4; ++y)
#pragma unroll
            for (int g2 = 0; g2 < 4; ++g2) {
                int row = mw + x * 16 + q * 4 + g2;
                int colc = nw + y * 16 + r;
                ct[row * 128 + colc] = (_Float16)acc[x][y][g2];
            }
    __syncthreads();
    int m = tid >> 1, half = tid & 1;
    const uint4* src = (const uint4*)sm;
    uint4* dstg =
        (uint4*)(Cg + ((size_t)(mt * 128 + m) * NC + nt * 128 + half * 64));
#pragma unroll
    for (int i = 0; i < 8; ++i) dstg[i] = src[m * 16 + half * 8 + i];
}

// ---------------- Recurrent kernel: 64 WGs (1/sample) x 1024 threads.
// Wave w covers H-cols j = w*16..w*16+15, all 4 gates (M-tiles g=0..3).
// A-frags (W^T int8) live in registers for the whole kernel; per step:
// 4x ds_read_b128 B-frag (h bytes) + 16 MFMA on the matrix pipe, then
// redistribute D via in-wave LDS, activations, shfl gate-exchange, ONE
// __syncthreads per step for the h double buffer.
__global__ __launch_bounds__(1024, 4) void lstm_rec(
    const unsigned short* __restrict__ gx, const uint4* __restrict__ afr,
    const float* __restrict__ sws, const float* __restrict__ bias,
    float* __restrict__ out) {
    int b = blockIdx.x, tid = threadIdx.x;
    int w = tid >> 6;          // wave 0..15
    int lane = tid & 63;
    int g = lane >> 4;         // gate 0..3 (i,f,g,o)
    int jj = lane & 15;
    int j = w * 16 + jj;       // H column 0..255
    int col = g * H_ + j;      // gate column 0..1023

    // A-fragments: af[gate][kt], 16 x uint4 = 64 VGPRs, loop-invariant.
    uint4 af[4][4];
#pragma unroll
    for (int gg = 0; gg < 4; ++gg)
#pragma unroll
        for (int kt = 0; kt < 4; ++kt)
            af[gg][kt] = afr[(((w * 4 + gg) * 4) + kt) * 64 + lane];

    float sc = sws[col];
    float bb = bias[col];

    __shared__ uint4 hq[2][16];              // 256 int8 h, double buffered
    __shared__ __align__(16) int sg[16 * 64];  // per-wave D redistribute
    if (tid < 16) hq[0][tid] = (uint4){0u, 0u, 0u, 0u};
    __syncthreads();

    float c = 0.f;               // live only in owner lanes (g==0)
    const _Float16* gxh = (const _Float16*)gx;
    size_t rowbase = (size_t)b * T_;
    float gxv = (float)gxh[rowbase * NC + col];

    for (int t = 0; t < T_; ++t) {
        size_t row = rowbase + t;
        // prefetch next step's g_x (clamped at the last step; value unused)
        size_t prow = rowbase + ((t < T_ - 1) ? (t + 1) : t);
        float nxv = (float)gxh[prow * NC + col];

        // B-frag: every lane supplies h bytes for its k-block (lane>>4);
        // all 16 B-columns therefore compute the same (correct) result.
        const char* hb = (const char*)hq[t & 1];
        i32x4 d0 = {0, 0, 0, 0}, d1 = {0, 0, 0, 0};
        i32x4 d2 = {0, 0, 0, 0}, d3 = {0, 0, 0, 0};
#pragma unroll
        for (int kt = 0; kt < 4; ++kt) {
            uint4 bf = *(const uint4*)(hb + kt * 64 + ((lane >> 4) << 4));
            i32x4 bfi = __builtin_bit_cast(i32x4, bf);
            d0 = __builtin_amdgcn_mfma_i32_16x16x64_i8(
                __builtin_bit_cast(i32x4, af[0][kt]), bfi, d0, 0, 0, 0);
            d1 = __builtin_amdgcn_mfma_i32_16x16x64_i8(
                __builtin_bit_cast(i32x4, af[1][kt]), bfi, d1, 0, 0, 0);
            d2 = __builtin_amdgcn_mfma_i32_16x16x64_i8(
                __builtin_bit_cast(i32x4, af[2][kt]), bfi, d2, 0, 0, 0);
            d3 = __builtin_amdgcn_mfma_i32_16x16x64_i8(
                __builtin_bit_cast(i32x4, af[3][kt]), bfi, d3, 0, 0, 0);
        }
        // D: col=lane&15, row=(lane>>4)*4+reg. Writers: col-0 lanes.
        // sg[w*64 + gate*16 + row] = pre-act; reader lane reads sg[w*64+lane]
        // (lane = g*16 + jj exactly matches gate*16 + row).
        if ((lane & 15) == 0) {
            int base = w * 64 + (lane >> 4) * 4;
            *(i32x4*)&sg[base + 0 * 16] = d0;
            *(i32x4*)&sg[base + 1 * 16] = d1;
            *(i32x4*)&sg[base + 2 * 16] = d2;
            *(i32x4*)&sg[base + 3 * 16] = d3;
        }
        __builtin_amdgcn_sched_barrier(0);  // keep read after in-wave writes
        int gi = sg[w * 64 + lane];
        float gpre = (float)gi * sc + gxv + bb;

        // unified activation: sigmoid for g in {0,1,3}, tanh for g==2
        bool isg = (g == 2);
        float arg = isg ? (-2.f * gpre) : (-gpre);
        float e = __expf(arg);
        float r = fastrcp(1.f + e);
        float v = isg ? (2.f * r - 1.f) : r;

        // in-wave gate exchange (no barrier): owner lanes (g==0) gather f,g,o
        float fv = __shfl(v, jj + 16, 64);
        float gv = __shfl(v, jj + 32, 64);
        float ov = __shfl(v, jj + 48, 64);

        if (g == 0) {  // owner lanes: c/h state for column j
            c = fv * c + v * gv;
            float ec = __expf(-2.f * c);
            float th = 2.f * fastrcp(1.f + ec) - 1.f;  // tanh(c), inf-safe
            float h = ov * th;
            out[row * H_ + j] = h;
            int qv = (int)rintf(h * 127.f);
            ((signed char*)hq[(t + 1) & 1])[j] = (signed char)qv;
        }
        __syncthreads();  // h buffer (t+1) complete before next step reads

        gxv = nxv;
    }
}

extern "C" void kernel_launch(void* const* d_in, const int* in_sizes, int n_in,
                              void* d_out, int out_size, void* d_ws,
                              size_t ws_size, hipStream_t stream) {
    const float* inputs = (const float*)d_in[0];
    const float* Wx = (const float*)d_in[1];
    const float* Wh = (const float*)d_in[2];
    const float* bias = (const float*)d_in[3];
    float* out = (float*)d_out;

    char* ws = (char*)d_ws;
    unsigned short* gxbuf = (unsigned short*)ws;   // 131072*1024 f16 = 256 MiB
    size_t off = (size_t)B_ * T_ * NC * 2;
    unsigned* afr = (unsigned*)(ws + off);         // 256 KiB int8 W_h A-frags
    off += (size_t)NC * 64 * 4;
    float* sws = (float*)(ws + off);               // 4 KiB scales
    off += (size_t)NC * 4;
    unsigned short* bxp = (unsigned short*)(ws + off);  // 256 KiB bf16 W_x
    off += (size_t)I_ * NC * 2;

    pack_wh<<<NC, 64, 0, stream>>>(Wh, afr, sws);
    pack_wx<<<(I_ * NC) / 256, 256, 0, stream>>>(Wx, bxp);
    gemm_gx<<<dim3((B_ * T_) / 128, NC / 128), 256, 0, stream>>>(inputs, bxp,
                                                                 gxbuf);
    lstm_rec<<<B_, 1024, 0, stream>>>(gxbuf, (const uint4*)afr, sws, bias, out);
}